// Round 5
// baseline (330.583 us; speedup 1.0000x reference)
//
#include <hip/hip_runtime.h>
#include <hip/hip_bf16.h>

typedef __bf16 bf16;
typedef __attribute__((ext_vector_type(8))) __bf16 bf16x8;
typedef __attribute__((ext_vector_type(4))) float f32x4;

#define T_TOK 8192
#define DIN   4096
#define DOUT  4096
#define RNK   16
#define NS    16
#define KLORA (NS * RNK)   // 256
#define GATE  0.12f

typedef __attribute__((address_space(1))) const void gconst_t;
typedef __attribute__((address_space(3))) void lds_t;

__device__ __forceinline__ void gload_lds16(const void* g, void* l) {
  __builtin_amdgcn_global_load_lds((gconst_t*)g, (lds_t*)l, 16, 0, 0);
}

#define BAR() do { asm volatile("" ::: "memory"); \
                   __builtin_amdgcn_s_barrier();  \
                   asm volatile("" ::: "memory"); } while (0)
#define VMW(n) asm volatile("s_waitcnt vmcnt(" #n ")" ::: "memory")
// counted lgkm wait + sched fence (rule #18: MFMAs are register-only and
// would otherwise be hoisted above the inline-asm wait)
#define LGKM(n) do { asm volatile("s_waitcnt lgkmcnt(" #n ")" ::: "memory"); \
                     __builtin_amdgcn_sched_barrier(0); } while (0)

// ---------------------------------------------------------------- prep kernels

__global__ __launch_bounds__(256)
void cast_x_kernel(const float* __restrict__ x, bf16* __restrict__ xb) {
  const long i = ((long)blockIdx.x * 256 + threadIdx.x) * 8;
  const float4 v0 = *(const float4*)(x + i);
  const float4 v1 = *(const float4*)(x + i + 4);
  bf16x8 o;
  o[0] = (bf16)v0.x; o[1] = (bf16)v0.y; o[2] = (bf16)v0.z; o[3] = (bf16)v0.w;
  o[4] = (bf16)v1.x; o[5] = (bf16)v1.y; o[6] = (bf16)v1.z; o[7] = (bf16)v1.w;
  *(bf16x8*)(xb + i) = o;
}

__global__ __launch_bounds__(256)
void build_bg_kernel(const float* __restrict__ B, const float* __restrict__ dw,
                     const int* __restrict__ sd, bf16* __restrict__ bg) {
  const int t = blockIdx.x * 256 + threadIdx.x;   // DOUT*256 threads
  const int o = t >> 8, k = t & 255, s = k >> 4, r = k & 15;
  const float w = dw[sd[s]];
  const float g = (w > GATE) ? w : 0.f;
  bg[t] = (bf16)(g * B[((size_t)s * DOUT + o) * RNK + r]);
}

__global__ __launch_bounds__(256)
void transpose_a_kernel(const float* __restrict__ A, bf16* __restrict__ at) {
  __shared__ float t[32][33];
  const int d0 = blockIdx.x * 32, k0 = blockIdx.y * 32;
  const int tx = threadIdx.x & 31, ty = threadIdx.x >> 5;
#pragma unroll
  for (int i = 0; i < 32; i += 8)
    t[ty + i][tx] = A[(size_t)(k0 + ty + i) * DIN + d0 + tx];
  __syncthreads();
#pragma unroll
  for (int i = 0; i < 32; i += 8)
    at[(size_t)(d0 + ty + i) * KLORA + k0 + tx] = (bf16)t[tx][ty + i];
}

// ---------------------------------------------------------------- 128^2 GEMM (W_eff only)
__global__ __launch_bounds__(256)
void gemm_bt(const bf16* __restrict__ Am, const bf16* __restrict__ Bm,
             const float* __restrict__ extra, bf16* __restrict__ outB,
             int M, int N, int K) {
  constexpr int BM = 128, BN = 128, BK = 32;
  __shared__ __align__(16) bf16 At[BM * BK];
  __shared__ __align__(16) bf16 Bt[BN * BK];

  const int tid  = threadIdx.x;
  const int wave = tid >> 6, lane = tid & 63;

  const int nwg = gridDim.x, bid = blockIdx.x;
  const int qq  = nwg >> 3;
  const int sw  = (bid & 7) * qq + (bid >> 3);
  const int ntN = N / BN;
  const long row0 = (long)(sw / ntN) * BM;
  const long col0 = (long)(sw % ntN) * BN;

  f32x4 acc[4][4] = {};
  const int kSteps = K / BK;

  auto stage = [&](int ks) {
    const long k0 = (long)ks * BK;
#pragma unroll
    for (int r = 0; r < 2; ++r) {
      const int off = tid * 16 + r * 4096;
      const int row = off >> 6;
      const int el  = (off & 63) >> 1;
      char* ldsA = (char*)At + (wave << 10) + (r << 12);
      char* ldsB = (char*)Bt + (wave << 10) + (r << 12);
      gload_lds16(Am + (row0 + row) * K + k0 + el, ldsA);
      gload_lds16(Bm + (col0 + row) * K + k0 + el, ldsB);
    }
  };

  stage(0);
  for (int ks = 0; ks < kSteps; ++ks) {
    __syncthreads();
    bf16x8 afr[4], bfr[4];
    const int koff = (lane >> 4) << 3;
    const int rsel = lane & 15;
    const int wr = wave >> 1, wc = wave & 1;
#pragma unroll
    for (int m = 0; m < 4; ++m)
      afr[m] = *(const bf16x8*)&At[((wr << 6) + (m << 4) + rsel) * BK + koff];
#pragma unroll
    for (int n = 0; n < 4; ++n)
      bfr[n] = *(const bf16x8*)&Bt[((wc << 6) + (n << 4) + rsel) * BK + koff];
    __syncthreads();
    if (ks + 1 < kSteps) stage(ks + 1);
#pragma unroll
    for (int m = 0; m < 4; ++m)
#pragma unroll
      for (int n = 0; n < 4; ++n)
        acc[m][n] = __builtin_amdgcn_mfma_f32_16x16x32_bf16(afr[m], bfr[n],
                                                            acc[m][n], 0, 0, 0);
  }

  const int wr = wave >> 1, wc = wave & 1;
#pragma unroll
  for (int m = 0; m < 4; ++m)
#pragma unroll
    for (int n = 0; n < 4; ++n)
#pragma unroll
      for (int j = 0; j < 4; ++j) {
        const long row = row0 + wr * 64 + m * 16 + ((lane >> 4) << 2) + j;
        const long col = col0 + wc * 64 + n * 16 + (lane & 15);
        outB[row * N + col] = (bf16)(acc[m][n][j] + extra[row * N + col]);
      }
}

// ---------------------------------------------------------------- 256^2 8-phase GEMM
// out[row][col] = sum_k Am[row][k]*Bm[col][k] + bias[col]   (f32 out)
// BM=BN=256, BK=64 (2 ksubs of 32). 8 waves (2M x 4N), 512 threads.
// LDS ring: 8 x 16KB half-tile slots; half H of K-tile t: H = 4t + {A-k0,B-k0,A-k1,B-k1},
// slot = H&7. One half staged per phase.
// Swizzle st_16x32: byte bit5 ^= row bit3; linear gload_lds dest +
// inverse-swizzled global source + swizzled ds_read address.
// Fragments double-buffered, read ONE PHASE AHEAD with counted lgkmcnt.
// Cross-tile landing guarantee: VMW(4) BEFORE the ph2-closing barrier
// (vmcnt is per-wave; only wait-then-barrier makes landings global).
__global__ __launch_bounds__(512, 2)
void gemm256(const bf16* __restrict__ Am, const bf16* __restrict__ Bm,
             const float* __restrict__ bias, float* __restrict__ out,
             int M, int N, int K) {
  extern __shared__ char smem[];
  const int tid  = threadIdx.x;
  const int wave = tid >> 6, lane = tid & 63;
  const int wr = wave >> 2, wc = wave & 3;       // 2 x 4 wave grid
  const int rsel = lane & 15, klane = lane >> 4;

  const int nwg = gridDim.x, bid = blockIdx.x;   // nwg multiple of 8
  const int sw  = (bid & 7) * (nwg >> 3) + (bid >> 3);
  const int ntN = N >> 8;
  const long row0 = (long)(sw / ntN) << 8;
  const long col0 = (long)(sw % ntN) << 8;

  // staging: dest (linear) = slot<<14 + (wave*2+r)<<10 + lane*16
  long srcA[2], srcB[2];
  int  ldsd[2];
  {
    const int rlo = lane >> 2;
    const int kbe = (((lane & 3) * 16) ^ (((lane >> 5) & 1) << 5)) >> 1;
#pragma unroll
    for (int r = 0; r < 2; ++r) {
      const int row = wave * 32 + r * 16 + rlo;
      srcA[r] = (row0 + row) * (long)K + kbe;
      srcB[r] = (col0 + row) * (long)K + kbe;
      ldsd[r] = (wave * 2 + r) << 10;
    }
  }

  const int nT = K >> 6;

  auto stage_half = [&](int H) {
    if (H >= 4 * nT) return;
    const int  slot = H & 7;
    const long kofs = (long)(H >> 2) * 64 + (long)((H >> 1) & 1) * 32;
    if (H & 1) {
#pragma unroll
      for (int r = 0; r < 2; ++r)
        gload_lds16(Bm + srcB[r] + kofs, smem + (slot << 14) + ldsd[r]);
    } else {
#pragma unroll
      for (int r = 0; r < 2; ++r)
        gload_lds16(Am + srcA[r] + kofs, smem + (slot << 14) + ldsd[r]);
    }
  };

  // read side: byte = row*64 + (klane*16 ^ ((row&8)<<2)); row&8 == rsel&8
  const int laneoff = rsel * 64 + ((klane * 16) ^ ((rsel & 8) << 2));

  f32x4 acc[8][4] = {};
  bf16x8 afr0[4], afr1[4], bfr0[4], bfr1[4];

  auto readA = [&](int slot, int mh, bf16x8* dst) {
    const char* base = smem + (slot << 14) + ((wr * 128 + mh * 64) << 6) + laneoff;
#pragma unroll
    for (int mi = 0; mi < 4; ++mi)
      dst[mi] = *(const bf16x8*)(base + (mi << 10));
  };
  auto readB = [&](int slot, bf16x8* dst) {
    const char* base = smem + (slot << 14) + ((wc * 64) << 6) + laneoff;
#pragma unroll
    for (int n = 0; n < 4; ++n)
      dst[n] = *(const bf16x8*)(base + (n << 10));
  };
  auto mfma16 = [&](int mh, const bf16x8* a, const bf16x8* bf) {
    __builtin_amdgcn_s_setprio(1);
#pragma unroll
    for (int mi = 0; mi < 4; ++mi)
#pragma unroll
      for (int n = 0; n < 4; ++n)
        acc[mh * 4 + mi][n] = __builtin_amdgcn_mfma_f32_16x16x32_bf16(
            a[mi], bf[n], acc[mh * 4 + mi][n], 0, 0, 0);
    __builtin_amdgcn_s_setprio(0);
  };

  // prologue — every frag read sits AFTER a barrier that follows all waves'
  // vmcnt wait for the halves it reads.
  stage_half(0); stage_half(1); stage_half(2); stage_half(3);
  VMW(4);                       // my halves 0,1 landed
  BAR();                        // ... now globally landed
  readB(1, bfr0); readA(0, 0, afr0);
  stage_half(4); stage_half(5); stage_half(6);
  VMW(6);                       // my halves 2,3 landed
  BAR();                        // ... globally landed (covers ph1's b|3 read)

  for (int t = 0; t < nT; ++t) {
    const int b  = (t & 1) << 2;
    const int b2 = b ^ 4;
    // ---- ph0: mh0 x ksub0  (afr0, bfr0)
    stage_half(4 * t + 7);
    BAR();
    readA(b | 0, 1, afr1);                       // for ph1
    LGKM(4);
    mfma16(0, afr0, bfr0);
    BAR();
    // ---- ph1: mh1 x ksub0  (afr1, bfr0)
    stage_half(4 * t + 8);
    BAR();
    readB(b | 3, bfr1); readA(b | 2, 0, afr0);   // for ph2
    LGKM(8);
    mfma16(1, afr1, bfr0);
    BAR();
    // ---- ph2: mh0 x ksub1  (afr0, bfr1)
    stage_half(4 * t + 9);
    BAR();
    readA(b | 2, 1, afr1);                       // for ph3
    LGKM(4);
    mfma16(0, afr0, bfr1);
    if (t == nT - 2) { VMW(0); } else { VMW(4); } // tile t+1 halves landed (mine)
    BAR();                                        // ... globally landed
    // ---- ph3: mh1 x ksub1  (afr1, bfr1)
    stage_half(4 * t + 10);
    BAR();
    if (t + 1 < nT) {
      readB(b2 | 1, bfr0); readA(b2 | 0, 0, afr0); // for next ph0 (tile t+1)
      LGKM(8);
    } else {
      LGKM(0);
    }
    mfma16(1, afr1, bfr1);
    BAR();
  }

  // epilogue — C/D layout: col = lane&15, row = (lane>>4)*4 + j
#pragma unroll
  for (int m = 0; m < 8; ++m)
#pragma unroll
    for (int n = 0; n < 4; ++n)
#pragma unroll
      for (int j = 0; j < 4; ++j) {
        const long row = row0 + wr * 128 + m * 16 + klane * 4 + j;
        const long col = col0 + wc * 64 + n * 16 + rsel;
        out[row * N + col] = acc[m][n][j] + bias[col];
      }
}

// ---------------------------------------------------------------- launch

extern "C" void kernel_launch(void* const* d_in, const int* in_sizes, int n_in,
                              void* d_out, int out_size, void* d_ws, size_t ws_size,
                              hipStream_t stream) {
  (void)in_sizes; (void)n_in; (void)out_size; (void)ws_size;
  const float* x  = (const float*)d_in[0];
  const float* W  = (const float*)d_in[1];
  const float* b  = (const float*)d_in[2];
  const float* A  = (const float*)d_in[3];
  const float* B  = (const float*)d_in[4];
  const float* dw = (const float*)d_in[5];
  const int*   sd = (const int*)d_in[6];
  float* out = (float*)d_out;

  char* ws = (char*)d_ws;
  bf16* xb    = (bf16*)(ws);                          // 64 MB
  bf16* weff  = (bf16*)(ws + ((size_t)64 << 20));     // 32 MB
  bf16* bg    = (bf16*)(ws + ((size_t)96 << 20));     //  2 MB
  bf16* acatT = (bf16*)(ws + ((size_t)98 << 20));     //  2 MB

  cast_x_kernel<<<(T_TOK * DIN / 8) / 256, 256, 0, stream>>>(x, xb);
  build_bg_kernel<<<(DOUT * KLORA) / 256, 256, 0, stream>>>(B, dw, sd, bg);
  transpose_a_kernel<<<dim3(DIN / 32, KLORA / 32), 256, 0, stream>>>(A, acatT);

  // W_eff = bf16(W + Bg @ AcatT^T)   : M=DOUT, N=DIN, K=256
  gemm_bt<<<(DOUT / 128) * (DIN / 128), 256, 0, stream>>>(
      bg, acatT, W, weff, DOUT, DIN, KLORA);

  // out = xb @ W_eff^T + b           : M=T, N=DOUT, K=DIN
  static_assert((T_TOK % 256) == 0 && (DOUT % 256) == 0 && (DIN % 64) == 0, "");
  hipFuncSetAttribute(reinterpret_cast<const void*>(gemm256),
                      hipFuncAttributeMaxDynamicSharedMemorySize, 131072);
  gemm256<<<(T_TOK / 256) * (DOUT / 256), 512, 131072, stream>>>(
      xb, weff, b, out, T_TOK, DOUT, DIN);
}

// Round 6
// 327.146 us; speedup vs baseline: 1.0105x; 1.0105x over previous
//
#include <hip/hip_runtime.h>
#include <hip/hip_bf16.h>

typedef __bf16 bf16;
typedef __attribute__((ext_vector_type(8))) __bf16 bf16x8;
typedef __attribute__((ext_vector_type(4))) float f32x4;

#define T_TOK 8192
#define DIN   4096
#define DOUT  4096
#define RNK   16
#define NS    16
#define KLORA (NS * RNK)   // 256
#define GATE  0.12f

typedef __attribute__((address_space(1))) const void gconst_t;
typedef __attribute__((address_space(3))) void lds_t;

__device__ __forceinline__ void gload_lds16(const void* g, void* l) {
  __builtin_amdgcn_global_load_lds((gconst_t*)g, (lds_t*)l, 16, 0, 0);
}

#define BAR() do { asm volatile("" ::: "memory"); \
                   __builtin_amdgcn_s_barrier();  \
                   asm volatile("" ::: "memory"); } while (0)
#define VMW(n) asm volatile("s_waitcnt vmcnt(" #n ")" ::: "memory")
// counted lgkm wait + sched fence (rule #18: MFMAs are register-only and
// would otherwise be hoisted above the inline-asm wait)
#define LGKM(n) do { asm volatile("s_waitcnt lgkmcnt(" #n ")" ::: "memory"); \
                     __builtin_amdgcn_sched_barrier(0); } while (0)

// ---------------------------------------------------------------- prep kernels

__global__ __launch_bounds__(256)
void cast_x_kernel(const float* __restrict__ x, bf16* __restrict__ xb) {
  const long i = ((long)blockIdx.x * 256 + threadIdx.x) * 8;
  const float4 v0 = *(const float4*)(x + i);
  const float4 v1 = *(const float4*)(x + i + 4);
  bf16x8 o;
  o[0] = (bf16)v0.x; o[1] = (bf16)v0.y; o[2] = (bf16)v0.z; o[3] = (bf16)v0.w;
  o[4] = (bf16)v1.x; o[5] = (bf16)v1.y; o[6] = (bf16)v1.z; o[7] = (bf16)v1.w;
  *(bf16x8*)(xb + i) = o;
}

__global__ __launch_bounds__(256)
void build_bg_kernel(const float* __restrict__ B, const float* __restrict__ dw,
                     const int* __restrict__ sd, bf16* __restrict__ bg) {
  const int t = blockIdx.x * 256 + threadIdx.x;   // DOUT*256 threads
  const int o = t >> 8, k = t & 255, s = k >> 4, r = k & 15;
  const float w = dw[sd[s]];
  const float g = (w > GATE) ? w : 0.f;
  bg[t] = (bf16)(g * B[((size_t)s * DOUT + o) * RNK + r]);
}

__global__ __launch_bounds__(256)
void transpose_a_kernel(const float* __restrict__ A, bf16* __restrict__ at) {
  __shared__ float t[32][33];
  const int d0 = blockIdx.x * 32, k0 = blockIdx.y * 32;
  const int tx = threadIdx.x & 31, ty = threadIdx.x >> 5;
#pragma unroll
  for (int i = 0; i < 32; i += 8)
    t[ty + i][tx] = A[(size_t)(k0 + ty + i) * DIN + d0 + tx];
  __syncthreads();
#pragma unroll
  for (int i = 0; i < 32; i += 8)
    at[(size_t)(d0 + ty + i) * KLORA + k0 + tx] = (bf16)t[tx][ty + i];
}

// ---------------------------------------------------------------- 128^2 GEMM (W_eff only)
__global__ __launch_bounds__(256)
void gemm_bt(const bf16* __restrict__ Am, const bf16* __restrict__ Bm,
             const float* __restrict__ extra, bf16* __restrict__ outB,
             int M, int N, int K) {
  constexpr int BM = 128, BN = 128, BK = 32;
  __shared__ __align__(16) bf16 At[BM * BK];
  __shared__ __align__(16) bf16 Bt[BN * BK];

  const int tid  = threadIdx.x;
  const int wave = tid >> 6, lane = tid & 63;

  const int nwg = gridDim.x, bid = blockIdx.x;
  const int qq  = nwg >> 3;
  const int sw  = (bid & 7) * qq + (bid >> 3);
  const int ntN = N / BN;
  const long row0 = (long)(sw / ntN) * BM;
  const long col0 = (long)(sw % ntN) * BN;

  f32x4 acc[4][4] = {};
  const int kSteps = K / BK;

  auto stage = [&](int ks) {
    const long k0 = (long)ks * BK;
#pragma unroll
    for (int r = 0; r < 2; ++r) {
      const int off = tid * 16 + r * 4096;
      const int row = off >> 6;
      const int el  = (off & 63) >> 1;
      char* ldsA = (char*)At + (wave << 10) + (r << 12);
      char* ldsB = (char*)Bt + (wave << 10) + (r << 12);
      gload_lds16(Am + (row0 + row) * K + k0 + el, ldsA);
      gload_lds16(Bm + (col0 + row) * K + k0 + el, ldsB);
    }
  };

  stage(0);
  for (int ks = 0; ks < kSteps; ++ks) {
    __syncthreads();
    bf16x8 afr[4], bfr[4];
    const int koff = (lane >> 4) << 3;
    const int rsel = lane & 15;
    const int wr = wave >> 1, wc = wave & 1;
#pragma unroll
    for (int m = 0; m < 4; ++m)
      afr[m] = *(const bf16x8*)&At[((wr << 6) + (m << 4) + rsel) * BK + koff];
#pragma unroll
    for (int n = 0; n < 4; ++n)
      bfr[n] = *(const bf16x8*)&Bt[((wc << 6) + (n << 4) + rsel) * BK + koff];
    __syncthreads();
    if (ks + 1 < kSteps) stage(ks + 1);
#pragma unroll
    for (int m = 0; m < 4; ++m)
#pragma unroll
      for (int n = 0; n < 4; ++n)
        acc[m][n] = __builtin_amdgcn_mfma_f32_16x16x32_bf16(afr[m], bfr[n],
                                                            acc[m][n], 0, 0, 0);
  }

  const int wr = wave >> 1, wc = wave & 1;
#pragma unroll
  for (int m = 0; m < 4; ++m)
#pragma unroll
    for (int n = 0; n < 4; ++n)
#pragma unroll
      for (int j = 0; j < 4; ++j) {
        const long row = row0 + wr * 64 + m * 16 + ((lane >> 4) << 2) + j;
        const long col = col0 + wc * 64 + n * 16 + (lane & 15);
        outB[row * N + col] = (bf16)(acc[m][n][j] + extra[row * N + col]);
      }
}

// ---------------------------------------------------------------- 256^2 GEMM, 4 phases/K-tile, 1 barrier/phase
// out[row][col] = sum_k Am[row][k]*Bm[col][k] + bias[col]   (f32 out)
// BM=BN=256, BK=64 (2 ksubs of 32). 8 waves (2M x 4N), 512 threads.
// Halves of tile t: A0=4t+0,B0=4t+1,A1=4t+2,B1=4t+3; slot = H&7 (16KB each).
// Stage cadence: ph0:4t+5, ph1:4t+6, ph2:4t+7, ph3:4t+8 (one half/phase).
// Waits: VMW(4) at end of ph0 (retires A1,B1 of t) and end of ph2 (retires
// A0,B0 of t+1); each is globalized by the NEXT phase's barrier, which the
// dependent ds_reads follow. VMW(0) at t==nT-1 ph0 (tail: skipped stages
// break the count). Frag reads one phase ahead with counted LGKM.
// WAR: slot overwritten at phase P last-read-issued <= P-2 (ledger-checked).
__global__ __launch_bounds__(512, 2)
void gemm256(const bf16* __restrict__ Am, const bf16* __restrict__ Bm,
             const float* __restrict__ bias, float* __restrict__ out,
             int M, int N, int K) {
  extern __shared__ char smem[];
  const int tid  = threadIdx.x;
  const int wave = tid >> 6, lane = tid & 63;
  const int wr = wave >> 2, wc = wave & 3;       // 2 x 4 wave grid
  const int rsel = lane & 15, klane = lane >> 4;

  const int nwg = gridDim.x, bid = blockIdx.x;   // nwg multiple of 8
  const int sw  = (bid & 7) * (nwg >> 3) + (bid >> 3);
  const int ntN = N >> 8;
  const long row0 = (long)(sw / ntN) << 8;
  const long col0 = (long)(sw % ntN) << 8;

  // staging: dest (linear) = slot<<14 + (wave*2+r)<<10 + lane*16
  long srcA[2], srcB[2];
  int  ldsd[2];
  {
    const int rlo = lane >> 2;
    const int kbe = (((lane & 3) * 16) ^ (((lane >> 5) & 1) << 5)) >> 1;
#pragma unroll
    for (int r = 0; r < 2; ++r) {
      const int row = wave * 32 + r * 16 + rlo;
      srcA[r] = (row0 + row) * (long)K + kbe;
      srcB[r] = (col0 + row) * (long)K + kbe;
      ldsd[r] = (wave * 2 + r) << 10;
    }
  }

  const int nT = K >> 6;

  auto stage_half = [&](int H) {
    if (H >= 4 * nT) return;
    const int  slot = H & 7;
    const long kofs = (long)(H >> 2) * 64 + (long)((H >> 1) & 1) * 32;
    if (H & 1) {
#pragma unroll
      for (int r = 0; r < 2; ++r)
        gload_lds16(Bm + srcB[r] + kofs, smem + (slot << 14) + ldsd[r]);
    } else {
#pragma unroll
      for (int r = 0; r < 2; ++r)
        gload_lds16(Am + srcA[r] + kofs, smem + (slot << 14) + ldsd[r]);
    }
  };

  // read side: byte = row*64 + (klane*16 ^ ((row&8)<<2)); row&8 == rsel&8
  const int laneoff = rsel * 64 + ((klane * 16) ^ ((rsel & 8) << 2));

  f32x4 acc[8][4] = {};
  bf16x8 afr0[4], afr1[4], bfr0[4], bfr1[4];

  auto readA = [&](int slot, int mh, bf16x8* dst) {
    const char* base = smem + (slot << 14) + ((wr * 128 + mh * 64) << 6) + laneoff;
#pragma unroll
    for (int mi = 0; mi < 4; ++mi)
      dst[mi] = *(const bf16x8*)(base + (mi << 10));
  };
  auto readB = [&](int slot, bf16x8* dst) {
    const char* base = smem + (slot << 14) + ((wc * 64) << 6) + laneoff;
#pragma unroll
    for (int n = 0; n < 4; ++n)
      dst[n] = *(const bf16x8*)(base + (n << 10));
  };
  auto mfma16 = [&](int mh, const bf16x8* a, const bf16x8* bf) {
    __builtin_amdgcn_s_setprio(1);
#pragma unroll
    for (int mi = 0; mi < 4; ++mi)
#pragma unroll
      for (int n = 0; n < 4; ++n)
        acc[mh * 4 + mi][n] = __builtin_amdgcn_mfma_f32_16x16x32_bf16(
            a[mi], bf[n], acc[mh * 4 + mi][n], 0, 0, 0);
    __builtin_amdgcn_s_setprio(0);
  };

  // prologue: stage halves 0..4 (10 loads); VMW(6) retires halves 0,1;
  // BAR globalizes; issue ph0's frag reads. Loop entry invariant:
  // outstanding = {2,3,4} -> after ph0's stage(5): {2,3,4,5} = 8 loads.
  stage_half(0); stage_half(1); stage_half(2); stage_half(3); stage_half(4);
  VMW(6);
  BAR();
  readB(1, bfr0); readA(0, 0, afr0);

  for (int t = 0; t < nT; ++t) {
    const int b  = (t & 1) << 2;
    const int b2 = b ^ 4;
    // ---- ph0: mh0 x ksub0  (afr0, bfr0)
    BAR();
    stage_half(4 * t + 5);
    readA(b | 0, 1, afr1);                       // for ph1
    LGKM(4);
    mfma16(0, afr0, bfr0);
    if (t == nT - 1) { VMW(0); } else { VMW(4); } // retires A1(t),B1(t)
    // ---- ph1: mh1 x ksub0  (afr1, bfr0)
    BAR();
    stage_half(4 * t + 6);
    readB(b | 3, bfr1); readA(b | 2, 0, afr0);   // for ph2
    LGKM(8);
    mfma16(1, afr1, bfr0);
    // ---- ph2: mh0 x ksub1  (afr0, bfr1)
    BAR();
    stage_half(4 * t + 7);
    readA(b | 2, 1, afr1);                       // for ph3
    LGKM(4);
    mfma16(0, afr0, bfr1);
    VMW(4);                                      // retires A0(t+1),B0(t+1)
    // ---- ph3: mh1 x ksub1  (afr1, bfr1)
    BAR();
    stage_half(4 * t + 8);
    if (t + 1 < nT) {
      readB(b2 | 1, bfr0); readA(b2 | 0, 0, afr0); // for next ph0
      LGKM(8);
    } else {
      LGKM(0);
    }
    mfma16(1, afr1, bfr1);
  }

  // epilogue — C/D layout: col = lane&15, row = (lane>>4)*4 + j
#pragma unroll
  for (int m = 0; m < 8; ++m)
#pragma unroll
    for (int n = 0; n < 4; ++n)
#pragma unroll
      for (int j = 0; j < 4; ++j) {
        const long row = row0 + wr * 128 + m * 16 + klane * 4 + j;
        const long col = col0 + wc * 64 + n * 16 + rsel;
        out[row * N + col] = acc[m][n][j] + bias[col];
      }
}

// ---------------------------------------------------------------- launch

extern "C" void kernel_launch(void* const* d_in, const int* in_sizes, int n_in,
                              void* d_out, int out_size, void* d_ws, size_t ws_size,
                              hipStream_t stream) {
  (void)in_sizes; (void)n_in; (void)out_size; (void)ws_size;
  const float* x  = (const float*)d_in[0];
  const float* W  = (const float*)d_in[1];
  const float* b  = (const float*)d_in[2];
  const float* A  = (const float*)d_in[3];
  const float* B  = (const float*)d_in[4];
  const float* dw = (const float*)d_in[5];
  const int*   sd = (const int*)d_in[6];
  float* out = (float*)d_out;

  char* ws = (char*)d_ws;
  bf16* xb    = (bf16*)(ws);                          // 64 MB
  bf16* weff  = (bf16*)(ws + ((size_t)64 << 20));     // 32 MB
  bf16* bg    = (bf16*)(ws + ((size_t)96 << 20));     //  2 MB
  bf16* acatT = (bf16*)(ws + ((size_t)98 << 20));     //  2 MB

  cast_x_kernel<<<(T_TOK * DIN / 8) / 256, 256, 0, stream>>>(x, xb);
  build_bg_kernel<<<(DOUT * KLORA) / 256, 256, 0, stream>>>(B, dw, sd, bg);
  transpose_a_kernel<<<dim3(DIN / 32, KLORA / 32), 256, 0, stream>>>(A, acatT);

  // W_eff = bf16(W + Bg @ AcatT^T)   : M=DOUT, N=DIN, K=256
  gemm_bt<<<(DOUT / 128) * (DIN / 128), 256, 0, stream>>>(
      bg, acatT, W, weff, DOUT, DIN, KLORA);

  // out = xb @ W_eff^T + b           : M=T, N=DOUT, K=DIN
  static_assert((T_TOK % 256) == 0 && (DOUT % 256) == 0 && (DIN % 64) == 0, "");
  hipFuncSetAttribute(reinterpret_cast<const void*>(gemm256),
                      hipFuncAttributeMaxDynamicSharedMemorySize, 131072);
  gemm256<<<(T_TOK / 256) * (DOUT / 256), 512, 131072, stream>>>(
      xb, weff, b, out, T_TOK, DOUT, DIN);
}